// Round 1
// baseline (392.108 us; speedup 1.0000x reference)
//
#include <hip/hip_runtime.h>

// ProxemicsFieldGenerator: 2-layer GAT on dense graph.
// b=16, n=1024, f0=32, h0=4, f1=16, F1H=64, f2=32, h1=1.

namespace {
constexpr int Nn  = 1024;
constexpr int F0  = 32;
constexpr int H0n = 4;
constexpr int F1n = 16;
constexpr int FH  = 64;   // H0n * F1n
constexpr int F2n = 32;
constexpr float LOG2E = 1.4426950408889634f;
constexpr float EPS   = 1e-5f;
constexpr float ALPHA = 0.2f;
}

// ---------------------------------------------------------------------------
// K1: instance-norm(x) -> h_prime1 [b,h,n,16], src1/dst1 [b,h,n]
// grid = 16 b * 4 ntiles, block = 256
// ---------------------------------------------------------------------------
__global__ __launch_bounds__(256) void k_norm_proj1(
    const float* __restrict__ x, const float* __restrict__ w1,
    const float* __restrict__ asrc, const float* __restrict__ adst,
    float* __restrict__ hp, float* __restrict__ src, float* __restrict__ dst)
{
  const int b     = blockIdx.x >> 2;
  const int ntile = blockIdx.x & 3;
  const int tid   = threadIdx.x;

  __shared__ float s_sum[8][32];
  __shared__ float s_ssq[8][32];
  __shared__ float s_mean[32];
  __shared__ float s_rstd[32];
  __shared__ float s_wt[H0n * F1n * F0];   // transposed: [h][o][f]
  __shared__ float s_as[H0n * F1n];
  __shared__ float s_ad[H0n * F1n];

  for (int idx = tid; idx < H0n * F1n * F0; idx += 256) {
    const int f  = idx & 31;
    const int ho = idx >> 5;               // h*16 + o
    const int h  = ho >> 4, o = ho & 15;
    s_wt[idx] = w1[(h * F0 + f) * F1n + o];
  }
  if (tid < H0n * F1n) { s_as[tid] = asrc[tid]; s_ad[tid] = adst[tid]; }

  // --- stats over n for each of 32 channels (redundant per ntile, cheap) ---
  const float* xb = x + (size_t)b * Nn * F0;
  const int c = tid & 31, sub = tid >> 5;
  float sum = 0.f, ssq = 0.f;
  for (int nn = sub; nn < Nn; nn += 8) {
    float v = xb[nn * F0 + c];
    sum += v; ssq += v * v;
  }
  s_sum[sub][c] = sum; s_ssq[sub][c] = ssq;
  __syncthreads();
  if (tid < 32) {
    float s = 0.f, q = 0.f;
#pragma unroll
    for (int k = 0; k < 8; k++) { s += s_sum[k][tid]; q += s_ssq[k][tid]; }
    const float mean = s * (1.f / Nn);
    const float var  = fmaf(-mean, mean, q * (1.f / Nn));
    s_mean[tid] = mean;
    s_rstd[tid] = rsqrtf(var + EPS);
  }
  __syncthreads();

  // --- one row per thread: normalize + project ---
  const int n = ntile * 256 + tid;
  float4 xn[F0 / 4];
  const float4* xrow = reinterpret_cast<const float4*>(xb + (size_t)n * F0);
#pragma unroll
  for (int f4 = 0; f4 < F0 / 4; f4++) {
    float4 v = xrow[f4];
    v.x = (v.x - s_mean[f4 * 4 + 0]) * s_rstd[f4 * 4 + 0];
    v.y = (v.y - s_mean[f4 * 4 + 1]) * s_rstd[f4 * 4 + 1];
    v.z = (v.z - s_mean[f4 * 4 + 2]) * s_rstd[f4 * 4 + 2];
    v.w = (v.w - s_mean[f4 * 4 + 3]) * s_rstd[f4 * 4 + 3];
    xn[f4] = v;
  }
  const float4* wt4 = reinterpret_cast<const float4*>(s_wt);
#pragma unroll 1
  for (int h = 0; h < H0n; h++) {
    float sdot = 0.f, ddot = 0.f;
    const int base = (b * H0n + h) * Nn + n;
    float4* hpo = reinterpret_cast<float4*>(hp + (size_t)base * F1n);
#pragma unroll 1
    for (int o4 = 0; o4 < F1n / 4; o4++) {
      float a0 = 0.f, a1 = 0.f, a2 = 0.f, a3 = 0.f;
#pragma unroll
      for (int f4 = 0; f4 < F0 / 4; f4++) {
        const float4 xv  = xn[f4];
        const float4 wv0 = wt4[(h * F1n + (o4 * 4 + 0)) * (F0 / 4) + f4];
        const float4 wv1 = wt4[(h * F1n + (o4 * 4 + 1)) * (F0 / 4) + f4];
        const float4 wv2 = wt4[(h * F1n + (o4 * 4 + 2)) * (F0 / 4) + f4];
        const float4 wv3 = wt4[(h * F1n + (o4 * 4 + 3)) * (F0 / 4) + f4];
        a0 = fmaf(xv.x, wv0.x, a0); a0 = fmaf(xv.y, wv0.y, a0);
        a0 = fmaf(xv.z, wv0.z, a0); a0 = fmaf(xv.w, wv0.w, a0);
        a1 = fmaf(xv.x, wv1.x, a1); a1 = fmaf(xv.y, wv1.y, a1);
        a1 = fmaf(xv.z, wv1.z, a1); a1 = fmaf(xv.w, wv1.w, a1);
        a2 = fmaf(xv.x, wv2.x, a2); a2 = fmaf(xv.y, wv2.y, a2);
        a2 = fmaf(xv.z, wv2.z, a2); a2 = fmaf(xv.w, wv2.w, a2);
        a3 = fmaf(xv.x, wv3.x, a3); a3 = fmaf(xv.y, wv3.y, a3);
        a3 = fmaf(xv.z, wv3.z, a3); a3 = fmaf(xv.w, wv3.w, a3);
      }
      sdot = fmaf(a0, s_as[h * F1n + o4 * 4 + 0], sdot);
      sdot = fmaf(a1, s_as[h * F1n + o4 * 4 + 1], sdot);
      sdot = fmaf(a2, s_as[h * F1n + o4 * 4 + 2], sdot);
      sdot = fmaf(a3, s_as[h * F1n + o4 * 4 + 3], sdot);
      ddot = fmaf(a0, s_ad[h * F1n + o4 * 4 + 0], ddot);
      ddot = fmaf(a1, s_ad[h * F1n + o4 * 4 + 1], ddot);
      ddot = fmaf(a2, s_ad[h * F1n + o4 * 4 + 2], ddot);
      ddot = fmaf(a3, s_ad[h * F1n + o4 * 4 + 3], ddot);
      hpo[o4] = make_float4(a0, a1, a2, a3);
    }
    src[base] = sdot;
    dst[base] = ddot;
  }
}

// ---------------------------------------------------------------------------
// K2: attention layer 0 + bias + elu + transpose -> x1 [b,n,64]
// grid = 64 (b,h) * 8 tiles(128 rows), block = 256 (128 rows x 2 j-halves)
// ---------------------------------------------------------------------------
__global__ __launch_bounds__(256) void k_attn1(
    const float* __restrict__ hp, const float* __restrict__ src,
    const float* __restrict__ dst, const float* __restrict__ bias,
    float* __restrict__ x1)
{
  const int bh   = blockIdx.x >> 3;
  const int tile = blockIdx.x & 7;
  const int tid  = threadIdx.x;
  const int r    = tid & 127;
  const int half = tid >> 7;

  __shared__ float s_dst[Nn];
  __shared__ float s_red[256];
  __shared__ float s_b[F1n];
  __shared__ float s_comb[128][F1n + 1];

  const float* dp = dst + bh * Nn;
  float lm = -1e30f;
  for (int j = tid; j < Nn; j += 256) {
    float v = dp[j];
    s_dst[j] = v;
    lm = fmaxf(lm, v);
  }
  s_red[tid] = lm;
  if (tid < F1n) s_b[tid] = bias[tid];
  __syncthreads();
  for (int s = 128; s > 0; s >>= 1) {
    if (tid < s) s_red[tid] = fmaxf(s_red[tid], s_red[tid + s]);
    __syncthreads();
  }
  const float dmax = s_red[0];

  const int i = tile * 128 + r;
  const float si = src[bh * Nn + i];
  const float t0 = si + dmax;
  const float m  = fmaxf(t0, ALPHA * t0);   // lrelu monotone => row max
  const float em = m * LOG2E;

  float acc[F1n];
#pragma unroll
  for (int k = 0; k < F1n; k++) acc[k] = 0.f;
  float psum = 0.f;

  const float4* hp4 = reinterpret_cast<const float4*>(hp + (size_t)bh * Nn * F1n);
  const int j0 = half * 512;
#pragma unroll 2
  for (int j = j0; j < j0 + 512; ++j) {
    const float tt = si + s_dst[j];
    const float u  = fmaxf(tt, ALPHA * tt);
    const float p  = exp2f(fmaf(u, LOG2E, -em));
    psum += p;
    const float4 v0 = hp4[(size_t)j * 4 + 0];
    const float4 v1 = hp4[(size_t)j * 4 + 1];
    const float4 v2 = hp4[(size_t)j * 4 + 2];
    const float4 v3 = hp4[(size_t)j * 4 + 3];
    acc[0]  = fmaf(p, v0.x, acc[0]);  acc[1]  = fmaf(p, v0.y, acc[1]);
    acc[2]  = fmaf(p, v0.z, acc[2]);  acc[3]  = fmaf(p, v0.w, acc[3]);
    acc[4]  = fmaf(p, v1.x, acc[4]);  acc[5]  = fmaf(p, v1.y, acc[5]);
    acc[6]  = fmaf(p, v1.z, acc[6]);  acc[7]  = fmaf(p, v1.w, acc[7]);
    acc[8]  = fmaf(p, v2.x, acc[8]);  acc[9]  = fmaf(p, v2.y, acc[9]);
    acc[10] = fmaf(p, v2.z, acc[10]); acc[11] = fmaf(p, v2.w, acc[11]);
    acc[12] = fmaf(p, v3.x, acc[12]); acc[13] = fmaf(p, v3.y, acc[13]);
    acc[14] = fmaf(p, v3.z, acc[14]); acc[15] = fmaf(p, v3.w, acc[15]);
  }

  if (half == 1) {
#pragma unroll
    for (int k = 0; k < F1n; k++) s_comb[r][k] = acc[k];
    s_comb[r][F1n] = psum;
  }
  __syncthreads();
  if (half == 0) {
#pragma unroll
    for (int k = 0; k < F1n; k++) acc[k] += s_comb[r][k];
    psum += s_comb[r][F1n];
    const float inv = 1.f / psum;
    const int b = bh >> 2, h = bh & 3;
    float4* xo4 = reinterpret_cast<float4*>(
        x1 + ((size_t)(b * Nn + i)) * FH + h * F1n);
#pragma unroll
    for (int k4 = 0; k4 < F1n / 4; k4++) {
      float4 v;
      v.x = fmaf(acc[k4 * 4 + 0], inv, s_b[k4 * 4 + 0]);
      v.y = fmaf(acc[k4 * 4 + 1], inv, s_b[k4 * 4 + 1]);
      v.z = fmaf(acc[k4 * 4 + 2], inv, s_b[k4 * 4 + 2]);
      v.w = fmaf(acc[k4 * 4 + 3], inv, s_b[k4 * 4 + 3]);
      v.x = v.x > 0.f ? v.x : exp2f(v.x * LOG2E) - 1.f;   // elu
      v.y = v.y > 0.f ? v.y : exp2f(v.y * LOG2E) - 1.f;
      v.z = v.z > 0.f ? v.z : exp2f(v.z * LOG2E) - 1.f;
      v.w = v.w > 0.f ? v.w : exp2f(v.w * LOG2E) - 1.f;
      xo4[k4] = v;
    }
  }
}

// ---------------------------------------------------------------------------
// K3: instance-norm(x1) -> h_prime2 [b,n,32], src2/dst2 [b,n]
// grid = 16 b * 4 ntiles, block = 256
// ---------------------------------------------------------------------------
__global__ __launch_bounds__(256) void k_norm_proj2(
    const float* __restrict__ x1, const float* __restrict__ w2,
    const float* __restrict__ asrc, const float* __restrict__ adst,
    float* __restrict__ hp, float* __restrict__ src, float* __restrict__ dst)
{
  const int b     = blockIdx.x >> 2;
  const int ntile = blockIdx.x & 3;
  const int tid   = threadIdx.x;

  __shared__ float s_sum[4][64];
  __shared__ float s_ssq[4][64];
  __shared__ float s_mean[64];
  __shared__ float s_rstd[64];
  __shared__ float s_wt[F2n * FH];   // transposed: [o][f]
  __shared__ float s_as[F2n];
  __shared__ float s_ad[F2n];

  for (int idx = tid; idx < F2n * FH; idx += 256) {
    const int f = idx & 63, o = idx >> 6;
    s_wt[idx] = w2[f * F2n + o];
  }
  if (tid < F2n) { s_as[tid] = asrc[tid]; s_ad[tid] = adst[tid]; }

  const float* xb = x1 + (size_t)b * Nn * FH;
  const int c = tid & 63, sub = tid >> 6;
  float sum = 0.f, ssq = 0.f;
  for (int nn = sub; nn < Nn; nn += 4) {
    float v = xb[nn * FH + c];
    sum += v; ssq += v * v;
  }
  s_sum[sub][c] = sum; s_ssq[sub][c] = ssq;
  __syncthreads();
  if (tid < 64) {
    float s = 0.f, q = 0.f;
#pragma unroll
    for (int k = 0; k < 4; k++) { s += s_sum[k][tid]; q += s_ssq[k][tid]; }
    const float mean = s * (1.f / Nn);
    const float var  = fmaf(-mean, mean, q * (1.f / Nn));
    s_mean[tid] = mean;
    s_rstd[tid] = rsqrtf(var + EPS);
  }
  __syncthreads();

  const int n = ntile * 256 + tid;
  float4 xn[FH / 4];
  const float4* xrow = reinterpret_cast<const float4*>(xb + (size_t)n * FH);
#pragma unroll
  for (int f4 = 0; f4 < FH / 4; f4++) {
    float4 v = xrow[f4];
    v.x = (v.x - s_mean[f4 * 4 + 0]) * s_rstd[f4 * 4 + 0];
    v.y = (v.y - s_mean[f4 * 4 + 1]) * s_rstd[f4 * 4 + 1];
    v.z = (v.z - s_mean[f4 * 4 + 2]) * s_rstd[f4 * 4 + 2];
    v.w = (v.w - s_mean[f4 * 4 + 3]) * s_rstd[f4 * 4 + 3];
    xn[f4] = v;
  }

  const int base = b * Nn + n;
  float4* hpo = reinterpret_cast<float4*>(hp + (size_t)base * F2n);
  const float4* wt4 = reinterpret_cast<const float4*>(s_wt);
  float sdot = 0.f, ddot = 0.f;
#pragma unroll 1
  for (int o4 = 0; o4 < F2n / 4; o4++) {
    float a0 = 0.f, a1 = 0.f, a2 = 0.f, a3 = 0.f;
#pragma unroll
    for (int f4 = 0; f4 < FH / 4; f4++) {
      const float4 xv  = xn[f4];
      const float4 wv0 = wt4[(o4 * 4 + 0) * (FH / 4) + f4];
      const float4 wv1 = wt4[(o4 * 4 + 1) * (FH / 4) + f4];
      const float4 wv2 = wt4[(o4 * 4 + 2) * (FH / 4) + f4];
      const float4 wv3 = wt4[(o4 * 4 + 3) * (FH / 4) + f4];
      a0 = fmaf(xv.x, wv0.x, a0); a0 = fmaf(xv.y, wv0.y, a0);
      a0 = fmaf(xv.z, wv0.z, a0); a0 = fmaf(xv.w, wv0.w, a0);
      a1 = fmaf(xv.x, wv1.x, a1); a1 = fmaf(xv.y, wv1.y, a1);
      a1 = fmaf(xv.z, wv1.z, a1); a1 = fmaf(xv.w, wv1.w, a1);
      a2 = fmaf(xv.x, wv2.x, a2); a2 = fmaf(xv.y, wv2.y, a2);
      a2 = fmaf(xv.z, wv2.z, a2); a2 = fmaf(xv.w, wv2.w, a2);
      a3 = fmaf(xv.x, wv3.x, a3); a3 = fmaf(xv.y, wv3.y, a3);
      a3 = fmaf(xv.z, wv3.z, a3); a3 = fmaf(xv.w, wv3.w, a3);
    }
    sdot = fmaf(a0, s_as[o4 * 4 + 0], sdot);
    sdot = fmaf(a1, s_as[o4 * 4 + 1], sdot);
    sdot = fmaf(a2, s_as[o4 * 4 + 2], sdot);
    sdot = fmaf(a3, s_as[o4 * 4 + 3], sdot);
    ddot = fmaf(a0, s_ad[o4 * 4 + 0], ddot);
    ddot = fmaf(a1, s_ad[o4 * 4 + 1], ddot);
    ddot = fmaf(a2, s_ad[o4 * 4 + 2], ddot);
    ddot = fmaf(a3, s_ad[o4 * 4 + 3], ddot);
    hpo[o4] = make_float4(a0, a1, a2, a3);
  }
  src[base] = sdot;
  dst[base] = ddot;
}

// ---------------------------------------------------------------------------
// K4: attention layer 1 + bias -> out [b,n,32]
// grid = 16 b * 16 tiles(64 rows), block = 256 (64 rows x 4 j-quarters)
// ---------------------------------------------------------------------------
__global__ __launch_bounds__(256) void k_attn2(
    const float* __restrict__ hp, const float* __restrict__ src,
    const float* __restrict__ dst, const float* __restrict__ bias,
    float* __restrict__ out)
{
  const int b    = blockIdx.x >> 4;
  const int tile = blockIdx.x & 15;
  const int tid  = threadIdx.x;
  const int r    = tid & 63;
  const int q    = tid >> 6;

  __shared__ float s_dst[Nn];
  __shared__ float s_red[256];
  __shared__ float s_b[F2n];
  __shared__ float s_comb[3][64][F2n + 1];

  const float* dp = dst + b * Nn;
  float lm = -1e30f;
  for (int j = tid; j < Nn; j += 256) {
    float v = dp[j];
    s_dst[j] = v;
    lm = fmaxf(lm, v);
  }
  s_red[tid] = lm;
  if (tid < F2n) s_b[tid] = bias[tid];
  __syncthreads();
  for (int s = 128; s > 0; s >>= 1) {
    if (tid < s) s_red[tid] = fmaxf(s_red[tid], s_red[tid + s]);
    __syncthreads();
  }
  const float dmax = s_red[0];

  const int i = tile * 64 + r;
  const float si = src[b * Nn + i];
  const float t0 = si + dmax;
  const float m  = fmaxf(t0, ALPHA * t0);
  const float em = m * LOG2E;

  float acc[F2n];
#pragma unroll
  for (int k = 0; k < F2n; k++) acc[k] = 0.f;
  float psum = 0.f;

  const float4* hp4 = reinterpret_cast<const float4*>(hp + (size_t)b * Nn * F2n);
  const int j0 = q * 256;
#pragma unroll 2
  for (int j = j0; j < j0 + 256; ++j) {
    const float tt = si + s_dst[j];
    const float u  = fmaxf(tt, ALPHA * tt);
    const float p  = exp2f(fmaf(u, LOG2E, -em));
    psum += p;
#pragma unroll
    for (int k4 = 0; k4 < F2n / 4; k4++) {
      const float4 v = hp4[(size_t)j * 8 + k4];
      acc[k4 * 4 + 0] = fmaf(p, v.x, acc[k4 * 4 + 0]);
      acc[k4 * 4 + 1] = fmaf(p, v.y, acc[k4 * 4 + 1]);
      acc[k4 * 4 + 2] = fmaf(p, v.z, acc[k4 * 4 + 2]);
      acc[k4 * 4 + 3] = fmaf(p, v.w, acc[k4 * 4 + 3]);
    }
  }

  if (q > 0) {
#pragma unroll
    for (int k = 0; k < F2n; k++) s_comb[q - 1][r][k] = acc[k];
    s_comb[q - 1][r][F2n] = psum;
  }
  __syncthreads();
  if (q == 0) {
#pragma unroll
    for (int qq = 0; qq < 3; qq++) {
#pragma unroll
      for (int k = 0; k < F2n; k++) acc[k] += s_comb[qq][r][k];
      psum += s_comb[qq][r][F2n];
    }
    const float inv = 1.f / psum;
    float4* oo = reinterpret_cast<float4*>(out + ((size_t)(b * Nn + i)) * F2n);
#pragma unroll
    for (int k4 = 0; k4 < F2n / 4; k4++) {
      float4 v;
      v.x = fmaf(acc[k4 * 4 + 0], inv, s_b[k4 * 4 + 0]);
      v.y = fmaf(acc[k4 * 4 + 1], inv, s_b[k4 * 4 + 1]);
      v.z = fmaf(acc[k4 * 4 + 2], inv, s_b[k4 * 4 + 2]);
      v.w = fmaf(acc[k4 * 4 + 3], inv, s_b[k4 * 4 + 3]);
      oo[k4] = v;
    }
  }
}

extern "C" void kernel_launch(void* const* d_in, const int* in_sizes, int n_in,
                              void* d_out, int out_size, void* d_ws, size_t ws_size,
                              hipStream_t stream) {
  (void)in_sizes; (void)n_in; (void)out_size; (void)ws_size;
  const float* x   = (const float*)d_in[0];
  const float* w1  = (const float*)d_in[1];
  const float* as1 = (const float*)d_in[2];
  const float* ad1 = (const float*)d_in[3];
  const float* b1  = (const float*)d_in[4];
  const float* w2  = (const float*)d_in[5];
  const float* as2 = (const float*)d_in[6];
  const float* ad2 = (const float*)d_in[7];
  const float* b2  = (const float*)d_in[8];
  float* out = (float*)d_out;

  float* ws   = (float*)d_ws;
  float* hp1  = ws;                    // 16*4*1024*16 = 1048576 floats
  float* src1 = hp1 + 1048576;         // 65536
  float* dst1 = src1 + 65536;          // 65536
  float* x1   = dst1 + 65536;          // 16*1024*64 = 1048576
  float* hp2  = x1 + 1048576;          // 16*1024*32 = 524288
  float* src2 = hp2 + 524288;          // 16384
  float* dst2 = src2 + 16384;          // 16384
  // total: 2,785,280 floats = 11.1 MB of workspace

  k_norm_proj1<<<64, 256, 0, stream>>>(x, w1, as1, ad1, hp1, src1, dst1);
  k_attn1<<<512, 256, 0, stream>>>(hp1, src1, dst1, b1, x1);
  k_norm_proj2<<<64, 256, 0, stream>>>(x1, w2, as2, ad2, hp2, src2, dst2);
  k_attn2<<<256, 256, 0, stream>>>(hp2, src2, dst2, b2, out);
}